// Round 1
// baseline (1050.684 us; speedup 1.0000x reference)
//
#include <hip/hip_runtime.h>
#include <cstdint>
#include <cstddef>

// ---------------------------------------------------------------------------
// GCN forward:
//   deg -> cs/cd/deg_idx -> CSR(dst) -> WF=proj_W@W1mid -> h1 = cs*(x@W1)
//   -> agg1 (gather-sum by dst) -> y = relu(agg1*cd + b1)
//   -> h2 = cs*(y@W2) -> agg2 -> out = agg2*cd + b2
// x = [logits | features@proj_W + proj_b | deg_table[deg_idx]] is never
// materialized: its W1 product is computed as three GEMM phases.
// ---------------------------------------------------------------------------

__global__ __launch_bounds__(256) void k_degrees(
    const int* __restrict__ src, const int* __restrict__ dst, int E,
    int* __restrict__ outd, int* __restrict__ ind)
{
    int i = blockIdx.x * 256 + threadIdx.x;
    if (i < E) {
        atomicAdd(&outd[src[i]], 1);
        atomicAdd(&ind[dst[i]], 1);
    }
}

__global__ __launch_bounds__(256) void k_norms(
    const int* __restrict__ outd, const int* __restrict__ ind, int N,
    float* __restrict__ cs, float* __restrict__ cd, int* __restrict__ didx)
{
    int i = blockIdx.x * 256 + threadIdx.x;
    if (i < N) {
        int od = outd[i], id = ind[i];
        cs[i] = rsqrtf((float)(od > 0 ? od : 1));
        cd[i] = rsqrtf((float)(id > 0 ? id : 1));
        int d = od + id;             // exact small ints; JAX gather clamps
        didx[i] = d > 511 ? 511 : d;
    }
}

// Single-block exclusive scan of in-degrees -> row_ptr, cursor
__global__ __launch_bounds__(1024) void k_scan(
    const int* __restrict__ ind, int N,
    int* __restrict__ rowp, int* __restrict__ cursor)
{
    __shared__ int sums[1024];
    int t = threadIdx.x;
    int chunk = (N + 1023) >> 10;
    int b = t * chunk, e = b + chunk;
    if (b > N) b = N;
    if (e > N) e = N;
    int s = 0;
    for (int i = b; i < e; ++i) s += ind[i];
    sums[t] = s;
    __syncthreads();
    for (int off = 1; off < 1024; off <<= 1) {
        int v = (t >= off) ? sums[t - off] : 0;
        __syncthreads();
        sums[t] += v;
        __syncthreads();
    }
    int run = (t == 0) ? 0 : sums[t - 1];
    for (int i = b; i < e; ++i) {
        rowp[i] = run;
        cursor[i] = run;
        run += ind[i];
    }
    if (t == 1023) rowp[N] = sums[1023];
}

__global__ __launch_bounds__(256) void k_csrfill(
    const int* __restrict__ src, const int* __restrict__ dst, int E,
    int* __restrict__ cursor, int* __restrict__ csr)
{
    int i = blockIdx.x * 256 + threadIdx.x;
    if (i < E) {
        int pos = atomicAdd(&cursor[dst[i]], 1);
        csr[pos] = src[i];
    }
}

// WF[k][j] = sum_m proj_W[k][m] * W1[64+m][j]   (512x128)
__global__ __launch_bounds__(256) void k_wf(
    const float* __restrict__ projW, const float* __restrict__ W1,
    float* __restrict__ WF)
{
    int idx = blockIdx.x * 256 + threadIdx.x;   // 512*128 threads
    int k = idx >> 7, j = idx & 127;
    const float* a = projW + (size_t)k * 128;
    float s = 0.f;
#pragma unroll 8
    for (int m = 0; m < 128; ++m) s = fmaf(a[m], W1[(size_t)(64 + m) * 128 + j], s);
    WF[idx] = s;
}

// cb[j] = sum_m proj_b[m] * W1[64+m][j]
__global__ void k_cb(const float* __restrict__ projb, const float* __restrict__ W1,
                     float* __restrict__ cb)
{
    int j = threadIdx.x;  // 128 threads
    float s = 0.f;
    for (int m = 0; m < 128; ++m) s = fmaf(projb[m], W1[(size_t)(64 + m) * 128 + j], s);
    cb[j] = s;
}

// h1[i][j] = cs[i] * ( logits[i]@W1[0:64] + features[i]@WF + deg_emb[i]@W1[192:256] + cb[j] )
// 128x128 block tile, 8x8 microtile, A transposed in LDS, B streamed from L2.
__global__ __launch_bounds__(256, 2) void k_h1(
    const float* __restrict__ logits, const float* __restrict__ features,
    const float* __restrict__ deg_table, const int* __restrict__ didx,
    const float* __restrict__ WF, const float* __restrict__ W1,
    const float* __restrict__ cb, const float* __restrict__ cs,
    float* __restrict__ h1, int N)
{
    constexpr int BM = 128, BK = 16;
    __shared__ float As[BK][BM + 4];   // [kk][row], pad keeps 16B align & banks spread
    int tid = threadIdx.x;
    int i0 = blockIdx.x * BM;
    int trow = tid >> 4, tcol = tid & 15;
    int la_row = tid >> 2;
    int la_k4 = (tid & 3) * 4;
    int nodeA0 = i0 + la_row;       if (nodeA0 >= N) nodeA0 = N - 1;
    int nodeA1 = i0 + la_row + 64;  if (nodeA1 >= N) nodeA1 = N - 1;

    float acc[8][8];
#pragma unroll
    for (int r = 0; r < 8; ++r)
#pragma unroll
        for (int c = 0; c < 8; ++c) acc[r][c] = 0.f;

    for (int phase = 0; phase < 3; ++phase) {
        const float* a0;
        const float* a1;
        const float* B;
        int Ksz;
        if (phase == 0) {
            a0 = features + (size_t)nodeA0 * 512;
            a1 = features + (size_t)nodeA1 * 512;
            B = WF; Ksz = 512;
        } else if (phase == 1) {
            a0 = logits + (size_t)nodeA0 * 64;
            a1 = logits + (size_t)nodeA1 * 64;
            B = W1; Ksz = 64;
        } else {
            a0 = deg_table + (size_t)didx[nodeA0] * 64;
            a1 = deg_table + (size_t)didx[nodeA1] * 64;
            B = W1 + (size_t)192 * 128; Ksz = 64;
        }
        for (int k0 = 0; k0 < Ksz; k0 += BK) {
            __syncthreads();
            float4 va0 = *(const float4*)(a0 + k0 + la_k4);
            float4 va1 = *(const float4*)(a1 + k0 + la_k4);
            As[la_k4 + 0][la_row] = va0.x;
            As[la_k4 + 1][la_row] = va0.y;
            As[la_k4 + 2][la_row] = va0.z;
            As[la_k4 + 3][la_row] = va0.w;
            As[la_k4 + 0][la_row + 64] = va1.x;
            As[la_k4 + 1][la_row + 64] = va1.y;
            As[la_k4 + 2][la_row + 64] = va1.z;
            As[la_k4 + 3][la_row + 64] = va1.w;
            __syncthreads();
            const float* Bk = B + (size_t)k0 * 128 + tcol * 8;
#pragma unroll
            for (int kk = 0; kk < BK; ++kk) {
                float4 av0 = *(const float4*)&As[kk][trow * 8];
                float4 av1 = *(const float4*)&As[kk][trow * 8 + 4];
                float4 bv0 = *(const float4*)(Bk + kk * 128);
                float4 bv1 = *(const float4*)(Bk + kk * 128 + 4);
                float a_[8] = {av0.x, av0.y, av0.z, av0.w, av1.x, av1.y, av1.z, av1.w};
                float b_[8] = {bv0.x, bv0.y, bv0.z, bv0.w, bv1.x, bv1.y, bv1.z, bv1.w};
#pragma unroll
                for (int r = 0; r < 8; ++r)
#pragma unroll
                    for (int c = 0; c < 8; ++c)
                        acc[r][c] = fmaf(a_[r], b_[c], acc[r][c]);
            }
        }
    }

    int col0 = tcol * 8;
    float cbv[8];
#pragma unroll
    for (int c = 0; c < 8; ++c) cbv[c] = cb[col0 + c];
#pragma unroll
    for (int r = 0; r < 8; ++r) {
        int node = i0 + trow * 8 + r;
        if (node < N) {
            float sc = cs[node];
            float4 o0, o1;
            o0.x = sc * (acc[r][0] + cbv[0]);
            o0.y = sc * (acc[r][1] + cbv[1]);
            o0.z = sc * (acc[r][2] + cbv[2]);
            o0.w = sc * (acc[r][3] + cbv[3]);
            o1.x = sc * (acc[r][4] + cbv[4]);
            o1.y = sc * (acc[r][5] + cbv[5]);
            o1.z = sc * (acc[r][6] + cbv[6]);
            o1.w = sc * (acc[r][7] + cbv[7]);
            *(float4*)(h1 + (size_t)node * 128 + col0) = o0;
            *(float4*)(h1 + (size_t)node * 128 + col0 + 4) = o1;
        }
    }
}

// Layer-1 aggregation: y[i] = relu( (sum_{e: dst=i} h1[src_e]) * cd[i] + b1 )
// one wave per node, 4 nodes per 256-thread block; 2 floats per lane.
__global__ __launch_bounds__(256) void k_agg1(
    const float* __restrict__ h1, const int* __restrict__ rowp,
    const int* __restrict__ csr, const float* __restrict__ cd,
    const float* __restrict__ b1, float* __restrict__ y, int N)
{
    int i = blockIdx.x * 4 + (threadIdx.x >> 6);
    if (i >= N) return;
    int lane = threadIdx.x & 63;
    int s0 = rowp[i], s1 = rowp[i + 1];
    float ax = 0.f, ay = 0.f;
    int e = s0;
    for (; e + 4 <= s1; e += 4) {
        int j0 = csr[e], j1 = csr[e + 1], j2 = csr[e + 2], j3 = csr[e + 3];
        float2 v0 = *(const float2*)(h1 + (size_t)j0 * 128 + lane * 2);
        float2 v1 = *(const float2*)(h1 + (size_t)j1 * 128 + lane * 2);
        float2 v2 = *(const float2*)(h1 + (size_t)j2 * 128 + lane * 2);
        float2 v3 = *(const float2*)(h1 + (size_t)j3 * 128 + lane * 2);
        ax += (v0.x + v1.x) + (v2.x + v3.x);
        ay += (v0.y + v1.y) + (v2.y + v3.y);
    }
    for (; e < s1; ++e) {
        int j = csr[e];
        float2 v = *(const float2*)(h1 + (size_t)j * 128 + lane * 2);
        ax += v.x; ay += v.y;
    }
    float cdi = cd[i];
    float2 o;
    o.x = fmaxf(fmaf(ax, cdi, b1[lane * 2 + 0]), 0.f);
    o.y = fmaxf(fmaf(ay, cdi, b1[lane * 2 + 1]), 0.f);
    *(float2*)(y + (size_t)i * 128 + lane * 2) = o;
}

// h2 = cs * (y @ W2)   M=100K, N=64, K=128
__global__ __launch_bounds__(256, 2) void k_h2(
    const float* __restrict__ y, const float* __restrict__ W2,
    const float* __restrict__ cs, float* __restrict__ h2, int N)
{
    constexpr int BM = 128, BK = 16;
    __shared__ float As[BK][BM + 4];
    __shared__ float Bs[BK][64];
    int tid = threadIdx.x;
    int i0 = blockIdx.x * BM;
    int trow = tid >> 4, tcol = tid & 15;
    int la_row = tid >> 2;
    int la_k4 = (tid & 3) * 4;
    int n0 = i0 + la_row;      if (n0 >= N) n0 = N - 1;
    int n1 = i0 + la_row + 64; if (n1 >= N) n1 = N - 1;
    const float* a0 = y + (size_t)n0 * 128;
    const float* a1 = y + (size_t)n1 * 128;
    int lb_kr = tid >> 4;          // 0..15
    int lb_col = (tid & 15) * 4;   // 0..60

    float acc[8][4];
#pragma unroll
    for (int r = 0; r < 8; ++r)
#pragma unroll
        for (int c = 0; c < 4; ++c) acc[r][c] = 0.f;

    for (int k0 = 0; k0 < 128; k0 += BK) {
        __syncthreads();
        float4 va0 = *(const float4*)(a0 + k0 + la_k4);
        float4 va1 = *(const float4*)(a1 + k0 + la_k4);
        As[la_k4 + 0][la_row] = va0.x;
        As[la_k4 + 1][la_row] = va0.y;
        As[la_k4 + 2][la_row] = va0.z;
        As[la_k4 + 3][la_row] = va0.w;
        As[la_k4 + 0][la_row + 64] = va1.x;
        As[la_k4 + 1][la_row + 64] = va1.y;
        As[la_k4 + 2][la_row + 64] = va1.z;
        As[la_k4 + 3][la_row + 64] = va1.w;
        *(float4*)&Bs[lb_kr][lb_col] =
            *(const float4*)(W2 + (size_t)(k0 + lb_kr) * 64 + lb_col);
        __syncthreads();
#pragma unroll
        for (int kk = 0; kk < BK; ++kk) {
            float4 av0 = *(const float4*)&As[kk][trow * 8];
            float4 av1 = *(const float4*)&As[kk][trow * 8 + 4];
            float4 bv = *(const float4*)&Bs[kk][tcol * 4];
            float a_[8] = {av0.x, av0.y, av0.z, av0.w, av1.x, av1.y, av1.z, av1.w};
            float b_[4] = {bv.x, bv.y, bv.z, bv.w};
#pragma unroll
            for (int r = 0; r < 8; ++r)
#pragma unroll
                for (int c = 0; c < 4; ++c)
                    acc[r][c] = fmaf(a_[r], b_[c], acc[r][c]);
        }
    }

#pragma unroll
    for (int r = 0; r < 8; ++r) {
        int node = i0 + trow * 8 + r;
        if (node < N) {
            float sc = cs[node];
            float4 o;
            o.x = sc * acc[r][0];
            o.y = sc * acc[r][1];
            o.z = sc * acc[r][2];
            o.w = sc * acc[r][3];
            *(float4*)(h2 + (size_t)node * 64 + tcol * 4) = o;
        }
    }
}

// Layer-2 aggregation: out[i] = (sum h2[src_e]) * cd[i] + b2
__global__ __launch_bounds__(256) void k_agg2(
    const float* __restrict__ h2, const int* __restrict__ rowp,
    const int* __restrict__ csr, const float* __restrict__ cd,
    const float* __restrict__ b2, float* __restrict__ out, int N)
{
    int i = blockIdx.x * 4 + (threadIdx.x >> 6);
    if (i >= N) return;
    int lane = threadIdx.x & 63;
    int s0 = rowp[i], s1 = rowp[i + 1];
    float a = 0.f;
    int e = s0;
    for (; e + 4 <= s1; e += 4) {
        int j0 = csr[e], j1 = csr[e + 1], j2 = csr[e + 2], j3 = csr[e + 3];
        float v0 = h2[(size_t)j0 * 64 + lane];
        float v1 = h2[(size_t)j1 * 64 + lane];
        float v2 = h2[(size_t)j2 * 64 + lane];
        float v3 = h2[(size_t)j3 * 64 + lane];
        a += (v0 + v1) + (v2 + v3);
    }
    for (; e < s1; ++e) a += h2[(size_t)csr[e] * 64 + lane];
    out[(size_t)i * 64 + lane] = fmaf(a, cd[i], b2[lane]);
}

extern "C" void kernel_launch(void* const* d_in, const int* in_sizes, int n_in,
                              void* d_out, int out_size, void* d_ws, size_t ws_size,
                              hipStream_t stream)
{
    const int* src = (const int*)d_in[0];
    const int* dst = (const int*)d_in[1];
    const float* logits = (const float*)d_in[2];
    const float* features = (const float*)d_in[3];
    const float* projW = (const float*)d_in[4];
    const float* projb = (const float*)d_in[5];
    const float* deg_table = (const float*)d_in[6];
    const float* W1 = (const float*)d_in[7];
    const float* b1 = (const float*)d_in[8];
    const float* W2 = (const float*)d_in[9];
    const float* b2 = (const float*)d_in[10];
    const int E = in_sizes[0];
    const int N = in_sizes[2] / 64;

    char* base = (char*)d_ws;
    size_t off = 0;
    auto alloc = [&](size_t bytes) -> void* {
        void* p = base + off;
        off += (bytes + 255) & ~(size_t)255;
        return p;
    };
    int* outd   = (int*)alloc((size_t)N * 4);
    int* ind    = (int*)alloc((size_t)N * 4);
    int* rowp   = (int*)alloc((size_t)(N + 1) * 4);
    int* cursor = (int*)alloc((size_t)N * 4);
    int* csr    = (int*)alloc((size_t)E * 4);
    int* didx   = (int*)alloc((size_t)N * 4);
    float* cs   = (float*)alloc((size_t)N * 4);
    float* cd   = (float*)alloc((size_t)N * 4);
    float* WF   = (float*)alloc((size_t)512 * 128 * 4);
    float* cb   = (float*)alloc((size_t)128 * 4);
    float* h1   = (float*)alloc((size_t)N * 128 * 4);
    float* yb   = (float*)alloc((size_t)N * 128 * 4);
    float* h2   = h1;   // h1 is dead after k_agg1; reuse its space
    float* outp = (float*)d_out;

    hipMemsetAsync(outd, 0, (size_t)N * 4, stream);
    hipMemsetAsync(ind, 0, (size_t)N * 4, stream);

    int eb = (E + 255) / 256;
    int nb = (N + 255) / 256;
    int mb = (N + 127) / 128;

    k_degrees<<<eb, 256, 0, stream>>>(src, dst, E, outd, ind);
    k_norms<<<nb, 256, 0, stream>>>(outd, ind, N, cs, cd, didx);
    k_scan<<<1, 1024, 0, stream>>>(ind, N, rowp, cursor);
    k_csrfill<<<eb, 256, 0, stream>>>(src, dst, E, cursor, csr);
    k_wf<<<256, 256, 0, stream>>>(projW, W1, WF);
    k_cb<<<1, 128, 0, stream>>>(projb, W1, cb);
    k_h1<<<mb, 256, 0, stream>>>(logits, features, deg_table, didx, WF, W1, cb, cs, h1, N);
    k_agg1<<<(N + 3) / 4, 256, 0, stream>>>(h1, rowp, csr, cd, b1, yb, N);
    k_h2<<<mb, 256, 0, stream>>>(yb, W2, cs, h2, N);
    k_agg2<<<(N + 3) / 4, 256, 0, stream>>>(h2, rowp, csr, cd, b2, outp, N);
}